// Round 2
// baseline (190.168 us; speedup 1.0000x reference)
//
#include <hip/hip_runtime.h>
#include <hip/hip_fp8.h>
#include <math.h>

typedef float v4f __attribute__((ext_vector_type(4)));

static constexpr int Bn = 8192;   // batch
static constexpr int Hn = 768;    // hidden
static constexpr float invB = 1.0f / 8192.0f;

__device__ __forceinline__ unsigned char cvt_e4m3(float x) {
    __hip_fp8_e4m3 t(x);          // OCP e4m3fn, RNE + satfinite
    return t.__x;
}

// tanh(x) = 1 - 2/(exp(2x)+1)
__device__ __forceinline__ float fast_tanh(float x) {
    float xc = fminf(fmaxf(x, -15.0f), 15.0f);
    float e = __expf(2.0f * xc);
    float r = __builtin_amdgcn_rcpf(e + 1.0f);
    return 1.0f - 2.0f * r;
}

// ---------------- fused prep: zero accumulators + fp32->fp8 all 5 tensors ----------------
__global__ void prep_kernel(const float* __restrict__ A,
                            const float* __restrict__ W1m, const float* __restrict__ W2m,
                            const float* __restrict__ W1v, const float* __restrict__ W2v,
                            unsigned char* __restrict__ A_f8,
                            unsigned char* __restrict__ W1m_f8, unsigned char* __restrict__ W2m_f8,
                            unsigned char* __restrict__ W1v_f8, unsigned char* __restrict__ W2v_f8,
                            float* __restrict__ zbuf, int nzero) {
    const int tid = blockIdx.x * blockDim.x + threadIdx.x;
    if (tid < nzero) zbuf[tid] = 0.0f;
    constexpr int A4 = Bn * Hn / 4;    // 4-elem units
    constexpr int W4 = Hn * Hn / 4;
    const int total = A4 + 4 * W4;
    const int stride = gridDim.x * blockDim.x;
    for (int i = tid; i < total; i += stride) {
        const float* s; unsigned char* d; int j;
        if (i < A4) { s = A; d = A_f8; j = i; }
        else {
            int k = i - A4; int w = k / W4; j = k - w * W4;
            s = (w == 0) ? W1m : (w == 1) ? W2m : (w == 2) ? W1v : W2v;
            d = (w == 0) ? W1m_f8 : (w == 1) ? W2m_f8 : (w == 2) ? W1v_f8 : W2v_f8;
        }
        float4 v = ((const float4*)s)[j];
        unsigned p = (unsigned)cvt_e4m3(v.x)
                   | ((unsigned)cvt_e4m3(v.y) << 8)
                   | ((unsigned)cvt_e4m3(v.z) << 16)
                   | ((unsigned)cvt_e4m3(v.w) << 24);
        ((unsigned*)d)[j] = p;
    }
}

// ============================================================================
// Barrier-free K-loop design, K=768 fully resident:
//  - activation strip staged ONCE into LDS (XOR-slotted 16B chunks vs row&7);
//  - W streamed straight to registers as MFMA b/a-operands (L2-resident, 0.59MB);
//  - K-permutation: macro-step K=64, lane(quad) takes phys k = ms*64+quad*16+[0,16);
//    both operands use the same permutation -> dot product unchanged, and W loads
//    become full-64B-line dwordx4.
// ============================================================================

// ---------------- LAYER 1: h1{m,v} = e4m3(tanh(A @ W^T + b)), one branch per block ----------------
__launch_bounds__(512, 2)
__global__ void gemm_l1(const unsigned char* __restrict__ A_g,
                        const unsigned char* __restrict__ Wm_g, const unsigned char* __restrict__ Wv_g,
                        const float* __restrict__ bm, const float* __restrict__ bv,
                        unsigned char* __restrict__ outm, unsigned char* __restrict__ outv) {
    __shared__ __align__(16) unsigned char As[64 * 768];   // 48 KB
    const int t = threadIdx.x;
    const int strip0 = blockIdx.x * 64;    // batch strip
    const int br = blockIdx.y;             // 0 = mu, 1 = logvar
    const unsigned char* __restrict__ Wg = br ? Wv_g : Wm_g;
    const float* __restrict__ bias = br ? bv : bm;
    unsigned char* __restrict__ out = br ? outv : outm;

    // ---- stage A strip once (64 rows x 768), chunk slot = c ^ (row&7)
    {
        const int row = t >> 3, c8 = t & 7;
        const unsigned char* src = A_g + (size_t)(strip0 + row) * Hn + c8 * 16;
        unsigned char* dst = As + row * 768;
#pragma unroll
        for (int j = 0; j < 6; ++j) {
            const int c = c8 + 8 * j;
            uint4 v = *(const uint4*)(src + j * 128);
            *(uint4*)(dst + ((c ^ (row & 7)) << 4)) = v;
        }
    }
    __syncthreads();

    const int w = t >> 6, lane = t & 63;
    const int lr = lane & 15, quad = lane >> 4;
    const int wc0 = w * 96;                // wave's 96 hidden cols

    // W operand: a-frag row = hidden col = lr; 16B covers phys k = ms*64 + quad*16
    const unsigned char* __restrict__ pW = Wg + (size_t)(wc0 + lr) * Hn + quad * 16;

    v4f acc[6][4] = {};        // [ct][rt]; D-row=hidden(quad*4+r), D-col=batch(lr)
    ulonglong2 Wf[2][6], Af[2][4];

#define L1_LOADS(s_, ms_) do {                                                              \
    _Pragma("unroll")                                                                       \
    for (int ct = 0; ct < 6; ++ct)                                                          \
        Wf[s_][ct] = *(const ulonglong2*)(pW + ct * (16 * Hn) + (ms_) * 64);                \
    _Pragma("unroll")                                                                       \
    for (int rt = 0; rt < 4; ++rt) {                                                        \
        const int row_ = rt * 16 + lr;                                                      \
        const int slot_ = ((ms_) * 4 + quad) ^ (row_ & 7);                                  \
        Af[s_][rt] = *(const ulonglong2*)&As[row_ * 768 + slot_ * 16];                      \
    } } while (0)

#define L1_MFMA(s_) do {                                                                    \
    _Pragma("unroll")                                                                       \
    for (int ct = 0; ct < 6; ++ct)                                                          \
    _Pragma("unroll")                                                                       \
    for (int rt = 0; rt < 4; ++rt) {                                                        \
        acc[ct][rt] = __builtin_amdgcn_mfma_f32_16x16x32_fp8_fp8((long)Wf[s_][ct].x, (long)Af[s_][rt].x, acc[ct][rt], 0, 0, 0); \
        acc[ct][rt] = __builtin_amdgcn_mfma_f32_16x16x32_fp8_fp8((long)Wf[s_][ct].y, (long)Af[s_][rt].y, acc[ct][rt], 0, 0, 0); \
    } } while (0)

    L1_LOADS(0, 0);
#pragma unroll
    for (int ms = 0; ms < 12; ++ms) {
        if (ms < 11) {
            if ((ms & 1) == 0) L1_LOADS(1, ms + 1); else L1_LOADS(0, ms + 1);
        }
        if ((ms & 1) == 0) L1_MFMA(0); else L1_MFMA(1);
    }
#undef L1_LOADS
#undef L1_MFMA

    // ---- epilogue: tanh -> fp8 dword pack -> LDS transpose (As is dead) -> 16B stores
    __syncthreads();   // all waves done reading As
#pragma unroll
    for (int ct = 0; ct < 6; ++ct) {
        const float4 bb = *(const float4*)&bias[wc0 + ct * 16 + quad * 4];
        const int c = w * 6 + ct;          // 16B chunk index of this dword's 4 hidden cols
#pragma unroll
        for (int rt = 0; rt < 4; ++rt) {
            const int row = rt * 16 + lr;  // batch row in strip
            v4f a = acc[ct][rt];
            unsigned p = (unsigned)cvt_e4m3(fast_tanh(a[0] + bb.x))
                       | ((unsigned)cvt_e4m3(fast_tanh(a[1] + bb.y)) << 8)
                       | ((unsigned)cvt_e4m3(fast_tanh(a[2] + bb.z)) << 16)
                       | ((unsigned)cvt_e4m3(fast_tanh(a[3] + bb.w)) << 24);
            *(unsigned*)&As[row * 768 + ((c ^ (row & 7)) << 4) + quad * 4] = p;
        }
    }
    __syncthreads();
#pragma unroll
    for (int i = 0; i < 6; ++i) {
        const int u = i * 512 + t;
        const int row = u / 48, c = u - row * 48;
        uint4 v = *(const uint4*)&As[row * 768 + ((c ^ (row & 7)) << 4)];
        *(uint4*)&out[(size_t)(strip0 + row) * Hn + c * 16] = v;
    }
}

// ---------------- LAYER 2: barrier-free K-loops + CLUB epilogue + finalize ----------------
// mfma(a = h1 frag, b = W frag) -> D-row = batch (quad*4+r), D-col = hidden (lr)
__device__ __forceinline__ void l2_gemm(const unsigned char* Hsrc, const unsigned char* pW,
                                        int lr, int quad, v4f acc[2][6]) {
    ulonglong2 Wf[2][6], Af[2][2];
#define L2_LOADS(s_, ms_) do {                                                              \
    _Pragma("unroll")                                                                       \
    for (int ct = 0; ct < 6; ++ct)                                                          \
        Wf[s_][ct] = *(const ulonglong2*)(pW + ct * (16 * Hn) + (ms_) * 64);                \
    _Pragma("unroll")                                                                       \
    for (int rt = 0; rt < 2; ++rt) {                                                        \
        const int row_ = rt * 16 + lr;                                                      \
        const int slot_ = ((ms_) * 4 + quad) ^ (row_ & 7);                                  \
        Af[s_][rt] = *(const ulonglong2*)&Hsrc[row_ * 768 + slot_ * 16];                    \
    } } while (0)

#define L2_MFMA(s_) do {                                                                    \
    _Pragma("unroll")                                                                       \
    for (int rt = 0; rt < 2; ++rt)                                                          \
    _Pragma("unroll")                                                                       \
    for (int ct = 0; ct < 6; ++ct) {                                                        \
        acc[rt][ct] = __builtin_amdgcn_mfma_f32_16x16x32_fp8_fp8((long)Af[s_][rt].x, (long)Wf[s_][ct].x, acc[rt][ct], 0, 0, 0); \
        acc[rt][ct] = __builtin_amdgcn_mfma_f32_16x16x32_fp8_fp8((long)Af[s_][rt].y, (long)Wf[s_][ct].y, acc[rt][ct], 0, 0, 0); \
    } } while (0)

    L2_LOADS(0, 0);
#pragma unroll
    for (int ms = 0; ms < 12; ++ms) {
        if (ms < 11) {
            if ((ms & 1) == 0) L2_LOADS(1, ms + 1); else L2_LOADS(0, ms + 1);
        }
        if ((ms & 1) == 0) L2_MFMA(0); else L2_MFMA(1);
    }
#undef L2_LOADS
#undef L2_MFMA
}

__launch_bounds__(512, 2)
__global__ void gemm_l2(const unsigned char* __restrict__ h1m_g, const unsigned char* __restrict__ h1v_g,
                        const unsigned char* __restrict__ Wm_g, const unsigned char* __restrict__ Wv_g,
                        const float* __restrict__ bm, const float* __restrict__ bv,
                        const float* __restrict__ mb,
                        float* __restrict__ cs, float* __restrict__ cs2,
                        float* __restrict__ siv, float* __restrict__ sivmu,
                        float* __restrict__ accum, float* __restrict__ outp) {
    __shared__ __align__(16) unsigned char Hs[2][32 * 768];   // h1m | h1v strips, 24 KB each
    const int t = threadIdx.x;
    const int strip0 = blockIdx.x * 32;    // batch strip

    // ---- stage both h1 strips once
    {
        const int row = t >> 4, c16 = t & 15;
        const size_t goff = (size_t)(strip0 + row) * Hn + c16 * 16;
#pragma unroll
        for (int b = 0; b < 2; ++b) {
            const unsigned char* src = (b ? h1v_g : h1m_g) + goff;
            unsigned char* dst = Hs[b] + row * 768;
#pragma unroll
            for (int j = 0; j < 3; ++j) {
                const int c = c16 + 16 * j;
                uint4 v = *(const uint4*)(src + j * 256);
                *(uint4*)(dst + ((c ^ (row & 7)) << 4)) = v;
            }
        }
    }
    __syncthreads();

    const int w = t >> 6, lane = t & 63;
    const int lr = lane & 15, quad = lane >> 4;
    const int wc0 = w * 96;

    v4f am[2][6] = {}, av[2][6] = {};      // [rt][ct]

    l2_gemm(&Hs[0][0], Wm_g + (size_t)(wc0 + lr) * Hn + quad * 16, lr, quad, am);
    l2_gemm(&Hs[1][0], Wv_g + (size_t)(wc0 + lr) * Hn + quad * 16, lr, quad, av);

    // ---------------- CLUB epilogue: col = wc0+ct*16+lr, row = strip0+rt*16+quad*4+r ----------------
    float pos = 0.f, q = 0.f;   // pos = sum iv*(mu-mb)^2 ; q = sum iv*mu^2
#pragma unroll
    for (int ct = 0; ct < 6; ++ct) {
        const int col = wc0 + ct * 16 + lr;
        const float bmc = bm[col], bvc = bv[col];
        float c1 = 0.f, c2 = 0.f, c3 = 0.f, c4 = 0.f;
#pragma unroll
        for (int rt = 0; rt < 2; ++rt) {
#pragma unroll
            for (int r = 0; r < 4; ++r) {
                const int row = strip0 + rt * 16 + quad * 4 + r;
                float mu = am[rt][ct][r] + bmc;
                float tv = fast_tanh(av[rt][ct][r] + bvc);
                float iv = __expf(-tv);
                float mbv = mb[(size_t)row * Hn + col];
                float d = mu - mbv;
                pos += iv * d * d;
                q   += iv * mu * mu;
                c1 += mu; c2 += mu * mu; c3 += iv; c4 += iv * mu;
            }
        }
        c1 += __shfl_xor(c1, 16); c1 += __shfl_xor(c1, 32);
        c2 += __shfl_xor(c2, 16); c2 += __shfl_xor(c2, 32);
        c3 += __shfl_xor(c3, 16); c3 += __shfl_xor(c3, 32);
        c4 += __shfl_xor(c4, 16); c4 += __shfl_xor(c4, 32);
        if (quad == 0) {
            atomicAdd(&cs[col], c1);
            atomicAdd(&cs2[col], c2);
            atomicAdd(&siv[col], c3);
            atomicAdd(&sivmu[col], c4);
        }
    }
    for (int off = 32; off > 0; off >>= 1) {
        pos += __shfl_down(pos, off);
        q   += __shfl_down(q, off);
    }
    __shared__ float redP[8], redQ[8];
    if (lane == 0) { redP[w] = pos; redQ[w] = q; }
    __syncthreads();
    __shared__ int is_last;
    if (t == 0) {
        float sp = 0.f, sq = 0.f;
#pragma unroll
        for (int i = 0; i < 8; ++i) { sp += redP[i]; sq += redQ[i]; }
        atomicAdd(&accum[0], sp);
        atomicAdd(&accum[1], sq);
        __threadfence();
        unsigned old = atomicAdd((unsigned int*)&accum[3], 1u);
        is_last = (old == gridDim.x * gridDim.y - 1) ? 1 : 0;
    }
    __syncthreads();
    if (is_last) {
        float term = 0.f;
        for (int h = t; h < Hn; h += 512) {
            float v1 = atomicAdd(&cs[h], 0.0f);
            float v2 = atomicAdd(&cs2[h], 0.0f);
            float v3 = atomicAdd(&siv[h], 0.0f);
            float v4 = atomicAdd(&sivmu[h], 0.0f);
            term += v3 * v2 - 2.0f * v4 * v1;
        }
        for (int off = 32; off > 0; off >>= 1) term += __shfl_down(term, off);
        __shared__ float redT[8];
        if (lane == 0) redT[w] = term;
        __syncthreads();
        if (t == 0) {
            float T = 0.f;
#pragma unroll
            for (int i = 0; i < 8; ++i) T += redT[i];
            float P = atomicAdd(&accum[0], 0.0f);
            float Q = atomicAdd(&accum[1], 0.0f);
            float pos_sum = -0.5f * P;
            float neg_sum = -0.5f * (T * invB + Q);
            outp[0] = pos_sum * invB;
            outp[1] = (pos_sum - neg_sum) * invB;
        }
    }
}

extern "C" void kernel_launch(void* const* d_in, const int* in_sizes, int n_in,
                              void* d_out, int out_size, void* d_ws, size_t ws_size,
                              hipStream_t stream) {
    const float* modal_a = (const float*)d_in[0];
    const float* modal_b = (const float*)d_in[1];
    const float* W1m = (const float*)d_in[2];
    const float* b1m = (const float*)d_in[3];
    const float* W2m = (const float*)d_in[4];
    const float* b2m = (const float*)d_in[5];
    const float* W1v = (const float*)d_in[6];
    const float* b1v = (const float*)d_in[7];
    const float* W2v = (const float*)d_in[8];
    const float* b2v = (const float*)d_in[9];
    float* out = (float*)d_out;

    char* ws = (char*)d_ws;
    constexpr size_t szA8 = (size_t)Bn * Hn;       // fp8 [B,H] = 6.29 MB
    constexpr size_t szW8 = (size_t)Hn * Hn;       // fp8 [H,H] = 0.59 MB
    unsigned char* A_f8   = (unsigned char*)(ws);
    unsigned char* h1m_f8 = (unsigned char*)(ws + szA8);
    unsigned char* h1v_f8 = (unsigned char*)(ws + 2 * szA8);
    unsigned char* W1m_f8 = (unsigned char*)(ws + 3 * szA8);
    unsigned char* W2m_f8 = (unsigned char*)(ws + 3 * szA8 + szW8);
    unsigned char* W1v_f8 = (unsigned char*)(ws + 3 * szA8 + 2 * szW8);
    unsigned char* W2v_f8 = (unsigned char*)(ws + 3 * szA8 + 3 * szW8);
    float* cs     = (float*)(ws + 3 * szA8 + 4 * szW8);
    float* cs2    = cs + Hn;
    float* siv    = cs + 2 * Hn;
    float* sivmu  = cs + 3 * Hn;
    float* accum  = cs + 4 * Hn;   // [0]=P [1]=Q [2]=pad [3]=ticket

    // 1. fused zero + fp32->fp8 convert (A + 4 W)
    prep_kernel<<<1280, 256, 0, stream>>>(modal_a, W1m, W2m, W1v, W2v,
                                          A_f8, W1m_f8, W2m_f8, W1v_f8, W2v_f8,
                                          cs, 4 * Hn + 8);

    // 2. layer-1: 128 batch strips x 2 branches, A-strip resident, W streamed from L2
    gemm_l1<<<dim3(Bn / 64, 2), 512, 0, stream>>>(
        A_f8, W1m_f8, W1v_f8, b1m, b1v, h1m_f8, h1v_f8);

    // 3. layer-2: 256 batch strips, h1 strips resident, W streamed; CLUB epilogue + finalize
    gemm_l2<<<dim3(Bn / 32), 512, 0, stream>>>(
        h1m_f8, h1v_f8, W2m_f8, W2v_f8, b2m, b2v, modal_b,
        cs, cs2, siv, sivmu, accum, out);
}

// Round 3
// 189.948 us; speedup vs baseline: 1.0012x; 1.0012x over previous
//
#include <hip/hip_runtime.h>
#include <hip/hip_fp8.h>
#include <math.h>

typedef float v4f __attribute__((ext_vector_type(4)));

static constexpr int Bn = 8192;   // batch
static constexpr int Hn = 768;    // hidden
static constexpr float invB = 1.0f / 8192.0f;

__device__ __forceinline__ unsigned char cvt_e4m3(float x) {
    __hip_fp8_e4m3 t(x);          // OCP e4m3fn, RNE + satfinite
    return t.__x;
}

__device__ __forceinline__ unsigned pack4_e4m3(float4 f) {
    return (unsigned)cvt_e4m3(f.x)
         | ((unsigned)cvt_e4m3(f.y) << 8)
         | ((unsigned)cvt_e4m3(f.z) << 16)
         | ((unsigned)cvt_e4m3(f.w) << 24);
}

// tanh(x) = 1 - 2/(exp(2x)+1)
__device__ __forceinline__ float fast_tanh(float x) {
    float xc = fminf(fmaxf(x, -15.0f), 15.0f);
    float e = __expf(2.0f * xc);
    float r = __builtin_amdgcn_rcpf(e + 1.0f);
    return 1.0f - 2.0f * r;
}

// ---------------- prep: zero accumulators + fp32->fp8 the 4 weight matrices ----------------
__global__ void prep_w(const float* __restrict__ W1m, const float* __restrict__ W2m,
                       const float* __restrict__ W1v, const float* __restrict__ W2v,
                       unsigned char* __restrict__ W1m_f8, unsigned char* __restrict__ W2m_f8,
                       unsigned char* __restrict__ W1v_f8, unsigned char* __restrict__ W2v_f8,
                       float* __restrict__ zbuf, int nzero) {
    const int tid = blockIdx.x * blockDim.x + threadIdx.x;
    if (tid < nzero) zbuf[tid] = 0.0f;
    constexpr int W4 = Hn * Hn / 4;    // 4-elem units
    const int total = 4 * W4;
    const int stride = gridDim.x * blockDim.x;
    for (int i = tid; i < total; i += stride) {
        int w = i / W4, j = i - w * W4;
        const float* s = (w == 0) ? W1m : (w == 1) ? W2m : (w == 2) ? W1v : W2v;
        unsigned char* d = (w == 0) ? W1m_f8 : (w == 1) ? W2m_f8 : (w == 2) ? W1v_f8 : W2v_f8;
        float4 v = ((const float4*)s)[j];
        ((unsigned*)d)[j] = pack4_e4m3(v);
    }
}

// ============================================================================
// Fully fused per-strip kernel. 256 blocks x 512 thr (1 block/CU), 32-row strip.
//   phase 1: A fp32 strip -> fp8 -> LDS Xs (XOR slot c ^ (row&15))
//   phase 2: layer-1 BOTH branches in one K-loop (shared A frags; W1m/W1v
//            streamed from L2 straight to regs, 1-deep double buffer;
//            K-permutation: phys k chunk = ms*4+quad, same on both operands)
//   phase 3: tanh -> fp8 pack -> h1m to Hm, h1v to Xs (A is dead)
//   phase 4: layer-2 BOTH branches in one K-loop (h1 frags from LDS)
//   phase 5: CLUB epilogue (unchanged math) + last-block finalize
// ============================================================================
__launch_bounds__(512, 2)
__global__ void club_fused(const float* __restrict__ A_g,
                           const unsigned char* __restrict__ W1m, const unsigned char* __restrict__ W1v,
                           const unsigned char* __restrict__ W2m, const unsigned char* __restrict__ W2v,
                           const float* __restrict__ b1m, const float* __restrict__ b1v,
                           const float* __restrict__ b2m, const float* __restrict__ b2v,
                           const float* __restrict__ mb,
                           float* __restrict__ cs, float* __restrict__ cs2,
                           float* __restrict__ siv, float* __restrict__ sivmu,
                           float* __restrict__ accum, float* __restrict__ outp) {
    __shared__ __align__(16) unsigned char Hm[32 * 768];   // 24 KB: h1m strip
    __shared__ __align__(16) unsigned char Xs[32 * 768];   // 24 KB: A-fp8, then h1v
    const int t = threadIdx.x;
    const int strip0 = blockIdx.x * 32;    // batch strip

    // ---- phase 1: stage + convert A strip (32 x 768 fp32 -> fp8)
    {
        const int row = t >> 4, seg = t & 15;
        const float* src = A_g + (size_t)(strip0 + row) * Hn;
#pragma unroll
        for (int j = 0; j < 3; ++j) {
            const int c = seg + 16 * j;            // 16B fp8 chunk = 16 cols
            float4 f0 = *(const float4*)(src + c * 16 + 0);
            float4 f1 = *(const float4*)(src + c * 16 + 4);
            float4 f2 = *(const float4*)(src + c * 16 + 8);
            float4 f3 = *(const float4*)(src + c * 16 + 12);
            uint4 p;
            p.x = pack4_e4m3(f0); p.y = pack4_e4m3(f1);
            p.z = pack4_e4m3(f2); p.w = pack4_e4m3(f3);
            *(uint4*)&Xs[row * 768 + ((c ^ (row & 15)) << 4)] = p;
        }
    }
    __syncthreads();

    const int w = t >> 6, lane = t & 63;
    const int lr = lane & 15, quad = lane >> 4;
    const int wc0 = w * 96;                // wave's 96 hidden cols

    // ---- phase 2: layer-1 dual-branch K-loop
    v4f am[6][2] = {}, av[6][2] = {};      // [ct][rt]; D-row=hidden(quad*4+r), D-col=batch(lr)
    {
        ulonglong2 Wm1[2][6], Wv1[2][6];
        const unsigned char* __restrict__ pWm = W1m + (size_t)(wc0 + lr) * Hn + quad * 16;
        const unsigned char* __restrict__ pWv = W1v + (size_t)(wc0 + lr) * Hn + quad * 16;

#define LDW1(s_, ms_) do {                                                                  \
    _Pragma("unroll")                                                                       \
    for (int ct = 0; ct < 6; ++ct) {                                                        \
        Wm1[s_][ct] = *(const ulonglong2*)(pWm + ct * (16 * Hn) + (ms_) * 64);              \
        Wv1[s_][ct] = *(const ulonglong2*)(pWv + ct * (16 * Hn) + (ms_) * 64);              \
    } } while (0)

#define FM1(s_, ms_) do {                                                                   \
    ulonglong2 Af[2];                                                                       \
    _Pragma("unroll")                                                                       \
    for (int rt = 0; rt < 2; ++rt) {                                                        \
        const int row_ = rt * 16 + lr;                                                      \
        const int k_ = (ms_) * 4 + quad;                                                    \
        Af[rt] = *(const ulonglong2*)&Xs[row_ * 768 + ((k_ ^ (row_ & 15)) << 4)];           \
    }                                                                                       \
    _Pragma("unroll")                                                                       \
    for (int ct = 0; ct < 6; ++ct)                                                          \
    _Pragma("unroll")                                                                       \
    for (int rt = 0; rt < 2; ++rt) {                                                        \
        am[ct][rt] = __builtin_amdgcn_mfma_f32_16x16x32_fp8_fp8((long)Wm1[s_][ct].x, (long)Af[rt].x, am[ct][rt], 0, 0, 0); \
        am[ct][rt] = __builtin_amdgcn_mfma_f32_16x16x32_fp8_fp8((long)Wm1[s_][ct].y, (long)Af[rt].y, am[ct][rt], 0, 0, 0); \
        av[ct][rt] = __builtin_amdgcn_mfma_f32_16x16x32_fp8_fp8((long)Wv1[s_][ct].x, (long)Af[rt].x, av[ct][rt], 0, 0, 0); \
        av[ct][rt] = __builtin_amdgcn_mfma_f32_16x16x32_fp8_fp8((long)Wv1[s_][ct].y, (long)Af[rt].y, av[ct][rt], 0, 0, 0); \
    } } while (0)

        LDW1(0, 0);
#pragma unroll
        for (int ms = 0; ms < 11; ++ms) {
            if ((ms & 1) == 0) { LDW1(1, ms + 1); FM1(0, ms); }
            else               { LDW1(0, ms + 1); FM1(1, ms); }
        }
        FM1(1, 11);
#undef LDW1
#undef FM1
    }

    __syncthreads();   // all waves done reading Xs (A)

    // ---- phase 3: tanh + fp8 pack -> Hm (mu), Xs (logvar)
#pragma unroll
    for (int ct = 0; ct < 6; ++ct) {
        const float4 bbm = *(const float4*)&b1m[wc0 + ct * 16 + quad * 4];
        const float4 bbv = *(const float4*)&b1v[wc0 + ct * 16 + quad * 4];
        const int cc = w * 6 + ct;         // 16B chunk of these 4 hidden cols (dword = quad)
#pragma unroll
        for (int rt = 0; rt < 2; ++rt) {
            const int row = rt * 16 + lr;  // batch row in strip
            v4f a = am[ct][rt];
            unsigned pm = (unsigned)cvt_e4m3(fast_tanh(a[0] + bbm.x))
                        | ((unsigned)cvt_e4m3(fast_tanh(a[1] + bbm.y)) << 8)
                        | ((unsigned)cvt_e4m3(fast_tanh(a[2] + bbm.z)) << 16)
                        | ((unsigned)cvt_e4m3(fast_tanh(a[3] + bbm.w)) << 24);
            v4f b = av[ct][rt];
            unsigned pv = (unsigned)cvt_e4m3(fast_tanh(b[0] + bbv.x))
                        | ((unsigned)cvt_e4m3(fast_tanh(b[1] + bbv.y)) << 8)
                        | ((unsigned)cvt_e4m3(fast_tanh(b[2] + bbv.z)) << 16)
                        | ((unsigned)cvt_e4m3(fast_tanh(b[3] + bbv.w)) << 24);
            const int off = row * 768 + ((cc ^ (row & 15)) << 4) + quad * 4;
            *(unsigned*)&Hm[off] = pm;
            *(unsigned*)&Xs[off] = pv;
        }
    }
    __syncthreads();

    // ---- phase 4: layer-2 dual-branch K-loop (h1 frags from LDS)
    v4f cm[2][6] = {}, cv[2][6] = {};      // [rt][ct]; D-row=batch(quad*4+r), D-col=hidden(lr)
    {
        ulonglong2 Wm2[2][6], Wv2[2][6];
        const unsigned char* __restrict__ pWm = W2m + (size_t)(wc0 + lr) * Hn + quad * 16;
        const unsigned char* __restrict__ pWv = W2v + (size_t)(wc0 + lr) * Hn + quad * 16;

#define LDW2(s_, ms_) do {                                                                  \
    _Pragma("unroll")                                                                       \
    for (int ct = 0; ct < 6; ++ct) {                                                        \
        Wm2[s_][ct] = *(const ulonglong2*)(pWm + ct * (16 * Hn) + (ms_) * 64);              \
        Wv2[s_][ct] = *(const ulonglong2*)(pWv + ct * (16 * Hn) + (ms_) * 64);              \
    } } while (0)

#define FM2(s_, ms_) do {                                                                   \
    ulonglong2 Am[2], Av[2];                                                                \
    _Pragma("unroll")                                                                       \
    for (int rt = 0; rt < 2; ++rt) {                                                        \
        const int row_ = rt * 16 + lr;                                                      \
        const int k_ = (ms_) * 4 + quad;                                                    \
        const int off_ = row_ * 768 + ((k_ ^ (row_ & 15)) << 4);                            \
        Am[rt] = *(const ulonglong2*)&Hm[off_];                                             \
        Av[rt] = *(const ulonglong2*)&Xs[off_];                                             \
    }                                                                                       \
    _Pragma("unroll")                                                                       \
    for (int rt = 0; rt < 2; ++rt)                                                          \
    _Pragma("unroll")                                                                       \
    for (int ct = 0; ct < 6; ++ct) {                                                        \
        cm[rt][ct] = __builtin_amdgcn_mfma_f32_16x16x32_fp8_fp8((long)Am[rt].x, (long)Wm2[s_][ct].x, cm[rt][ct], 0, 0, 0); \
        cm[rt][ct] = __builtin_amdgcn_mfma_f32_16x16x32_fp8_fp8((long)Am[rt].y, (long)Wm2[s_][ct].y, cm[rt][ct], 0, 0, 0); \
        cv[rt][ct] = __builtin_amdgcn_mfma_f32_16x16x32_fp8_fp8((long)Av[rt].x, (long)Wv2[s_][ct].x, cv[rt][ct], 0, 0, 0); \
        cv[rt][ct] = __builtin_amdgcn_mfma_f32_16x16x32_fp8_fp8((long)Av[rt].y, (long)Wv2[s_][ct].y, cv[rt][ct], 0, 0, 0); \
    } } while (0)

        LDW2(0, 0);
#pragma unroll
        for (int ms = 0; ms < 11; ++ms) {
            if ((ms & 1) == 0) { LDW2(1, ms + 1); FM2(0, ms); }
            else               { LDW2(0, ms + 1); FM2(1, ms); }
        }
        FM2(1, 11);
#undef LDW2
#undef FM2
    }

    // ---- phase 5: CLUB epilogue: col = wc0+ct*16+lr, row = strip0+rt*16+quad*4+r
    float pos = 0.f, q = 0.f;   // pos = sum iv*(mu-mb)^2 ; q = sum iv*mu^2
#pragma unroll
    for (int ct = 0; ct < 6; ++ct) {
        const int col = wc0 + ct * 16 + lr;
        const float bmc = b2m[col], bvc = b2v[col];
        float c1 = 0.f, c2 = 0.f, c3 = 0.f, c4 = 0.f;
#pragma unroll
        for (int rt = 0; rt < 2; ++rt) {
#pragma unroll
            for (int r = 0; r < 4; ++r) {
                const int row = strip0 + rt * 16 + quad * 4 + r;
                float mu = cm[rt][ct][r] + bmc;
                float tv = fast_tanh(cv[rt][ct][r] + bvc);
                float iv = __expf(-tv);
                float mbv = mb[(size_t)row * Hn + col];
                float d = mu - mbv;
                pos += iv * d * d;
                q   += iv * mu * mu;
                c1 += mu; c2 += mu * mu; c3 += iv; c4 += iv * mu;
            }
        }
        c1 += __shfl_xor(c1, 16); c1 += __shfl_xor(c1, 32);
        c2 += __shfl_xor(c2, 16); c2 += __shfl_xor(c2, 32);
        c3 += __shfl_xor(c3, 16); c3 += __shfl_xor(c3, 32);
        c4 += __shfl_xor(c4, 16); c4 += __shfl_xor(c4, 32);
        if (quad == 0) {
            atomicAdd(&cs[col], c1);
            atomicAdd(&cs2[col], c2);
            atomicAdd(&siv[col], c3);
            atomicAdd(&sivmu[col], c4);
        }
    }
    for (int off = 32; off > 0; off >>= 1) {
        pos += __shfl_down(pos, off);
        q   += __shfl_down(q, off);
    }
    __shared__ float redP[8], redQ[8];
    if (lane == 0) { redP[w] = pos; redQ[w] = q; }
    __syncthreads();
    __shared__ int is_last;
    if (t == 0) {
        float sp = 0.f, sq = 0.f;
#pragma unroll
        for (int i = 0; i < 8; ++i) { sp += redP[i]; sq += redQ[i]; }
        atomicAdd(&accum[0], sp);
        atomicAdd(&accum[1], sq);
        __threadfence();
        unsigned old = atomicAdd((unsigned int*)&accum[3], 1u);
        is_last = (old == gridDim.x - 1) ? 1 : 0;
    }
    __syncthreads();
    if (is_last) {
        float term = 0.f;
        for (int h = t; h < Hn; h += 512) {
            float v1 = atomicAdd(&cs[h], 0.0f);
            float v2 = atomicAdd(&cs2[h], 0.0f);
            float v3 = atomicAdd(&siv[h], 0.0f);
            float v4 = atomicAdd(&sivmu[h], 0.0f);
            term += v3 * v2 - 2.0f * v4 * v1;
        }
        for (int off = 32; off > 0; off >>= 1) term += __shfl_down(term, off);
        __shared__ float redT[8];
        if (lane == 0) redT[w] = term;
        __syncthreads();
        if (t == 0) {
            float T = 0.f;
#pragma unroll
            for (int i = 0; i < 8; ++i) T += redT[i];
            float P = atomicAdd(&accum[0], 0.0f);
            float Q = atomicAdd(&accum[1], 0.0f);
            float pos_sum = -0.5f * P;
            float neg_sum = -0.5f * (T * invB + Q);
            outp[0] = pos_sum * invB;
            outp[1] = (pos_sum - neg_sum) * invB;
        }
    }
}

extern "C" void kernel_launch(void* const* d_in, const int* in_sizes, int n_in,
                              void* d_out, int out_size, void* d_ws, size_t ws_size,
                              hipStream_t stream) {
    const float* modal_a = (const float*)d_in[0];
    const float* modal_b = (const float*)d_in[1];
    const float* W1m = (const float*)d_in[2];
    const float* b1m = (const float*)d_in[3];
    const float* W2m = (const float*)d_in[4];
    const float* b2m = (const float*)d_in[5];
    const float* W1v = (const float*)d_in[6];
    const float* b1v = (const float*)d_in[7];
    const float* W2v = (const float*)d_in[8];
    const float* b2v = (const float*)d_in[9];
    float* out = (float*)d_out;

    char* ws = (char*)d_ws;
    constexpr size_t szW8 = (size_t)Hn * Hn;       // fp8 [H,H] = 0.59 MB
    unsigned char* W1m_f8 = (unsigned char*)(ws);
    unsigned char* W2m_f8 = (unsigned char*)(ws + szW8);
    unsigned char* W1v_f8 = (unsigned char*)(ws + 2 * szW8);
    unsigned char* W2v_f8 = (unsigned char*)(ws + 3 * szW8);
    float* cs     = (float*)(ws + 4 * szW8);
    float* cs2    = cs + Hn;
    float* siv    = cs + 2 * Hn;
    float* sivmu  = cs + 3 * Hn;
    float* accum  = cs + 4 * Hn;   // [0]=P [1]=Q [2]=pad [3]=ticket

    // 1. zero accumulators + fp32->fp8 convert the 4 weight matrices
    prep_w<<<576, 256, 0, stream>>>(W1m, W2m, W1v, W2v,
                                    W1m_f8, W2m_f8, W1v_f8, W2v_f8,
                                    cs, 4 * Hn + 8);

    // 2. fully fused per-strip MLP + CLUB (256 blocks = 1/CU, 32-row strips)
    club_fused<<<dim3(Bn / 32), 512, 0, stream>>>(
        modal_a, W1m_f8, W1v_f8, W2m_f8, W2v_f8,
        b1m, b1v, b2m, b2v, modal_b,
        cs, cs2, siv, sivmu, accum, out);
}

// Round 4
// 188.013 us; speedup vs baseline: 1.0115x; 1.0103x over previous
//
#include <hip/hip_runtime.h>
#include <hip/hip_fp8.h>
#include <math.h>

typedef float v4f __attribute__((ext_vector_type(4)));

static constexpr int Bn = 8192;   // batch
static constexpr int Hn = 768;    // hidden
static constexpr float invB = 1.0f / 8192.0f;

__device__ __forceinline__ unsigned char cvt_e4m3(float x) {
    __hip_fp8_e4m3 t(x);          // OCP e4m3fn, RNE + satfinite
    return t.__x;
}

__device__ __forceinline__ unsigned pack4_e4m3(float4 f) {
    return (unsigned)cvt_e4m3(f.x)
         | ((unsigned)cvt_e4m3(f.y) << 8)
         | ((unsigned)cvt_e4m3(f.z) << 16)
         | ((unsigned)cvt_e4m3(f.w) << 24);
}

// tanh(x) = 1 - 2/(exp(2x)+1)
__device__ __forceinline__ float fast_tanh(float x) {
    float xc = fminf(fmaxf(x, -15.0f), 15.0f);
    float e = __expf(2.0f * xc);
    float r = __builtin_amdgcn_rcpf(e + 1.0f);
    return 1.0f - 2.0f * r;
}

// ---------------- prep: zero accumulators + fp32->fp8 the 4 weight matrices ----------------
__global__ void prep_w(const float* __restrict__ W1m, const float* __restrict__ W2m,
                       const float* __restrict__ W1v, const float* __restrict__ W2v,
                       unsigned char* __restrict__ W1m_f8, unsigned char* __restrict__ W2m_f8,
                       unsigned char* __restrict__ W1v_f8, unsigned char* __restrict__ W2v_f8,
                       float* __restrict__ zbuf, int nzero) {
    const int tid = blockIdx.x * blockDim.x + threadIdx.x;
    if (tid < nzero) zbuf[tid] = 0.0f;
    constexpr int W4 = Hn * Hn / 4;    // 4-elem units
    const int total = 4 * W4;
    const int stride = gridDim.x * blockDim.x;
    for (int i = tid; i < total; i += stride) {
        int w = i / W4, j = i - w * W4;
        const float* s = (w == 0) ? W1m : (w == 1) ? W2m : (w == 2) ? W1v : W2v;
        unsigned char* d = (w == 0) ? W1m_f8 : (w == 1) ? W2m_f8 : (w == 2) ? W1v_f8 : W2v_f8;
        float4 v = ((const float4*)s)[j];
        ((unsigned*)d)[j] = pack4_e4m3(v);
    }
}

// ============================================================================
// Fused per-strip kernel, round-4 shape: 256 blocks x 1024 thr (16 waves =
// 4 waves/SIMD), 32-row strip, each wave owns 48 hidden cols (3 x 16).
//   phase 1: A fp32 strip -> fp8 -> LDS Xs (XOR slot c ^ (row&15))
//   phase 2: layer-1 BOTH branches, W streamed L2->regs (JIT, TLP-hidden),
//            .x/.y MFMA passes split so no back-to-back dependent MFMA
//   phase 3: tanh -> fp8 pack -> h1m to Hm, h1v to Xs (A dead)
//   phase 4: layer-2 BOTH branches, same scheme
//   phase 5: CLUB epilogue + last-block finalize
// ============================================================================
__launch_bounds__(1024, 4)
__global__ void club_fused(const float* __restrict__ A_g,
                           const unsigned char* __restrict__ W1m, const unsigned char* __restrict__ W1v,
                           const unsigned char* __restrict__ W2m, const unsigned char* __restrict__ W2v,
                           const float* __restrict__ b1m, const float* __restrict__ b1v,
                           const float* __restrict__ b2m, const float* __restrict__ b2v,
                           const float* __restrict__ mb,
                           float* __restrict__ cs, float* __restrict__ cs2,
                           float* __restrict__ siv, float* __restrict__ sivmu,
                           float* __restrict__ accum, float* __restrict__ outp) {
    __shared__ __align__(16) unsigned char Hm[32 * 768];   // 24 KB: h1m strip
    __shared__ __align__(16) unsigned char Xs[32 * 768];   // 24 KB: A-fp8, then h1v
    const int t = threadIdx.x;
    const int strip0 = blockIdx.x * 32;    // batch strip

    // ---- phase 1: stage + convert A strip (32 x 768 fp32 -> fp8), 1536 16B chunks
    for (int c = t; c < 1536; c += 1024) {
        const int row = c / 48, cc = c - row * 48;
        const float* src = A_g + (size_t)(strip0 + row) * Hn + cc * 16;
        float4 f0 = *(const float4*)(src + 0);
        float4 f1 = *(const float4*)(src + 4);
        float4 f2 = *(const float4*)(src + 8);
        float4 f3 = *(const float4*)(src + 12);
        uint4 p;
        p.x = pack4_e4m3(f0); p.y = pack4_e4m3(f1);
        p.z = pack4_e4m3(f2); p.w = pack4_e4m3(f3);
        *(uint4*)&Xs[row * 768 + ((cc ^ (row & 15)) << 4)] = p;
    }
    __syncthreads();

    const int w = t >> 6, lane = t & 63;
    const int lr = lane & 15, quad = lane >> 4;
    const int wc0 = w * 48;                // wave's 48 hidden cols

    // ---- phase 2: layer-1 dual-branch K-loop
    v4f am[3][2] = {}, av[3][2] = {};      // [ct][rt]; D-row=hidden(quad*4+r), D-col=batch(lr)
    {
        const unsigned char* __restrict__ pWm = W1m + (size_t)(wc0 + lr) * Hn + quad * 16;
        const unsigned char* __restrict__ pWv = W1v + (size_t)(wc0 + lr) * Hn + quad * 16;
#pragma unroll
        for (int ms = 0; ms < 12; ++ms) {
            ulonglong2 wmf[3], wvf[3], af[2];
#pragma unroll
            for (int ct = 0; ct < 3; ++ct) {
                wmf[ct] = *(const ulonglong2*)(pWm + ct * (16 * Hn) + ms * 64);
                wvf[ct] = *(const ulonglong2*)(pWv + ct * (16 * Hn) + ms * 64);
            }
#pragma unroll
            for (int rt = 0; rt < 2; ++rt) {
                const int row_ = rt * 16 + lr;
                const int k_ = ms * 4 + quad;
                af[rt] = *(const ulonglong2*)&Xs[row_ * 768 + ((k_ ^ (row_ & 15)) << 4)];
            }
#pragma unroll
            for (int ct = 0; ct < 3; ++ct)
#pragma unroll
                for (int rt = 0; rt < 2; ++rt) {
                    am[ct][rt] = __builtin_amdgcn_mfma_f32_16x16x32_fp8_fp8((long)wmf[ct].x, (long)af[rt].x, am[ct][rt], 0, 0, 0);
                    av[ct][rt] = __builtin_amdgcn_mfma_f32_16x16x32_fp8_fp8((long)wvf[ct].x, (long)af[rt].x, av[ct][rt], 0, 0, 0);
                }
#pragma unroll
            for (int ct = 0; ct < 3; ++ct)
#pragma unroll
                for (int rt = 0; rt < 2; ++rt) {
                    am[ct][rt] = __builtin_amdgcn_mfma_f32_16x16x32_fp8_fp8((long)wmf[ct].y, (long)af[rt].y, am[ct][rt], 0, 0, 0);
                    av[ct][rt] = __builtin_amdgcn_mfma_f32_16x16x32_fp8_fp8((long)wvf[ct].y, (long)af[rt].y, av[ct][rt], 0, 0, 0);
                }
        }
    }

    __syncthreads();   // all waves done reading Xs (A)

    // ---- phase 3: tanh + fp8 pack -> Hm (mu), Xs (logvar)
#pragma unroll
    for (int ct = 0; ct < 3; ++ct) {
        const float4 bbm = *(const float4*)&b1m[wc0 + ct * 16 + quad * 4];
        const float4 bbv = *(const float4*)&b1v[wc0 + ct * 16 + quad * 4];
        const int cc = w * 3 + ct;         // 16B chunk of these 4 hidden cols (dword = quad)
#pragma unroll
        for (int rt = 0; rt < 2; ++rt) {
            const int row = rt * 16 + lr;  // batch row in strip
            v4f a = am[ct][rt];
            unsigned pm = (unsigned)cvt_e4m3(fast_tanh(a[0] + bbm.x))
                        | ((unsigned)cvt_e4m3(fast_tanh(a[1] + bbm.y)) << 8)
                        | ((unsigned)cvt_e4m3(fast_tanh(a[2] + bbm.z)) << 16)
                        | ((unsigned)cvt_e4m3(fast_tanh(a[3] + bbm.w)) << 24);
            v4f b = av[ct][rt];
            unsigned pv = (unsigned)cvt_e4m3(fast_tanh(b[0] + bbv.x))
                        | ((unsigned)cvt_e4m3(fast_tanh(b[1] + bbv.y)) << 8)
                        | ((unsigned)cvt_e4m3(fast_tanh(b[2] + bbv.z)) << 16)
                        | ((unsigned)cvt_e4m3(fast_tanh(b[3] + bbv.w)) << 24);
            const int off = row * 768 + ((cc ^ (row & 15)) << 4) + quad * 4;
            *(unsigned*)&Hm[off] = pm;
            *(unsigned*)&Xs[off] = pv;
        }
    }
    __syncthreads();

    // ---- phase 4: layer-2 dual-branch K-loop (h1 frags from LDS)
    v4f cm[2][3] = {}, cv[2][3] = {};      // [rt][ct]; D-row=batch(quad*4+r), D-col=hidden(lr)
    {
        const unsigned char* __restrict__ pWm = W2m + (size_t)(wc0 + lr) * Hn + quad * 16;
        const unsigned char* __restrict__ pWv = W2v + (size_t)(wc0 + lr) * Hn + quad * 16;
#pragma unroll
        for (int ms = 0; ms < 12; ++ms) {
            ulonglong2 wmf[3], wvf[3], amf[2], avf[2];
#pragma unroll
            for (int ct = 0; ct < 3; ++ct) {
                wmf[ct] = *(const ulonglong2*)(pWm + ct * (16 * Hn) + ms * 64);
                wvf[ct] = *(const ulonglong2*)(pWv + ct * (16 * Hn) + ms * 64);
            }
#pragma unroll
            for (int rt = 0; rt < 2; ++rt) {
                const int row_ = rt * 16 + lr;
                const int k_ = ms * 4 + quad;
                const int off_ = row_ * 768 + ((k_ ^ (row_ & 15)) << 4);
                amf[rt] = *(const ulonglong2*)&Hm[off_];
                avf[rt] = *(const ulonglong2*)&Xs[off_];
            }
#pragma unroll
            for (int rt = 0; rt < 2; ++rt)
#pragma unroll
                for (int ct = 0; ct < 3; ++ct) {
                    cm[rt][ct] = __builtin_amdgcn_mfma_f32_16x16x32_fp8_fp8((long)amf[rt].x, (long)wmf[ct].x, cm[rt][ct], 0, 0, 0);
                    cv[rt][ct] = __builtin_amdgcn_mfma_f32_16x16x32_fp8_fp8((long)avf[rt].x, (long)wvf[ct].x, cv[rt][ct], 0, 0, 0);
                }
#pragma unroll
            for (int rt = 0; rt < 2; ++rt)
#pragma unroll
                for (int ct = 0; ct < 3; ++ct) {
                    cm[rt][ct] = __builtin_amdgcn_mfma_f32_16x16x32_fp8_fp8((long)amf[rt].y, (long)wmf[ct].y, cm[rt][ct], 0, 0, 0);
                    cv[rt][ct] = __builtin_amdgcn_mfma_f32_16x16x32_fp8_fp8((long)avf[rt].y, (long)wvf[ct].y, cv[rt][ct], 0, 0, 0);
                }
        }
    }

    // ---- phase 5: CLUB epilogue: col = wc0+ct*16+lr, row = strip0+rt*16+quad*4+r
    float pos = 0.f, q = 0.f;   // pos = sum iv*(mu-mb)^2 ; q = sum iv*mu^2
#pragma unroll
    for (int ct = 0; ct < 3; ++ct) {
        const int col = wc0 + ct * 16 + lr;
        const float bmc = b2m[col], bvc = b2v[col];
        float c1 = 0.f, c2 = 0.f, c3 = 0.f, c4 = 0.f;
#pragma unroll
        for (int rt = 0; rt < 2; ++rt) {
#pragma unroll
            for (int r = 0; r < 4; ++r) {
                const int row = strip0 + rt * 16 + quad * 4 + r;
                float mu = cm[rt][ct][r] + bmc;
                float tv = fast_tanh(cv[rt][ct][r] + bvc);
                float iv = __expf(-tv);
                float mbv = mb[(size_t)row * Hn + col];
                float d = mu - mbv;
                pos += iv * d * d;
                q   += iv * mu * mu;
                c1 += mu; c2 += mu * mu; c3 += iv; c4 += iv * mu;
            }
        }
        c1 += __shfl_xor(c1, 16); c1 += __shfl_xor(c1, 32);
        c2 += __shfl_xor(c2, 16); c2 += __shfl_xor(c2, 32);
        c3 += __shfl_xor(c3, 16); c3 += __shfl_xor(c3, 32);
        c4 += __shfl_xor(c4, 16); c4 += __shfl_xor(c4, 32);
        if (quad == 0) {
            atomicAdd(&cs[col], c1);
            atomicAdd(&cs2[col], c2);
            atomicAdd(&siv[col], c3);
            atomicAdd(&sivmu[col], c4);
        }
    }
    for (int off = 32; off > 0; off >>= 1) {
        pos += __shfl_down(pos, off);
        q   += __shfl_down(q, off);
    }
    __shared__ float redP[16], redQ[16];
    if (lane == 0) { redP[w] = pos; redQ[w] = q; }
    __syncthreads();
    __shared__ int is_last;
    if (t == 0) {
        float sp = 0.f, sq = 0.f;
#pragma unroll
        for (int i = 0; i < 16; ++i) { sp += redP[i]; sq += redQ[i]; }
        atomicAdd(&accum[0], sp);
        atomicAdd(&accum[1], sq);
        __threadfence();
        unsigned old = atomicAdd((unsigned int*)&accum[3], 1u);
        is_last = (old == gridDim.x - 1) ? 1 : 0;
    }
    __syncthreads();
    if (is_last) {
        float term = 0.f;
        for (int h = t; h < Hn; h += 1024) {
            float v1 = atomicAdd(&cs[h], 0.0f);
            float v2 = atomicAdd(&cs2[h], 0.0f);
            float v3 = atomicAdd(&siv[h], 0.0f);
            float v4 = atomicAdd(&sivmu[h], 0.0f);
            term += v3 * v2 - 2.0f * v4 * v1;
        }
        for (int off = 32; off > 0; off >>= 1) term += __shfl_down(term, off);
        __shared__ float redT[16];
        if (lane == 0) redT[w] = term;
        __syncthreads();
        if (t == 0) {
            float T = 0.f;
#pragma unroll
            for (int i = 0; i < 16; ++i) T += redT[i];
            float P = atomicAdd(&accum[0], 0.0f);
            float Q = atomicAdd(&accum[1], 0.0f);
            float pos_sum = -0.5f * P;
            float neg_sum = -0.5f * (T * invB + Q);
            outp[0] = pos_sum * invB;
            outp[1] = (pos_sum - neg_sum) * invB;
        }
    }
}

extern "C" void kernel_launch(void* const* d_in, const int* in_sizes, int n_in,
                              void* d_out, int out_size, void* d_ws, size_t ws_size,
                              hipStream_t stream) {
    const float* modal_a = (const float*)d_in[0];
    const float* modal_b = (const float*)d_in[1];
    const float* W1m = (const float*)d_in[2];
    const float* b1m = (const float*)d_in[3];
    const float* W2m = (const float*)d_in[4];
    const float* b2m = (const float*)d_in[5];
    const float* W1v = (const float*)d_in[6];
    const float* b1v = (const float*)d_in[7];
    const float* W2v = (const float*)d_in[8];
    const float* b2v = (const float*)d_in[9];
    float* out = (float*)d_out;

    char* ws = (char*)d_ws;
    constexpr size_t szW8 = (size_t)Hn * Hn;       // fp8 [H,H] = 0.59 MB
    unsigned char* W1m_f8 = (unsigned char*)(ws);
    unsigned char* W2m_f8 = (unsigned char*)(ws + szW8);
    unsigned char* W1v_f8 = (unsigned char*)(ws + 2 * szW8);
    unsigned char* W2v_f8 = (unsigned char*)(ws + 3 * szW8);
    float* cs     = (float*)(ws + 4 * szW8);
    float* cs2    = cs + Hn;
    float* siv    = cs + 2 * Hn;
    float* sivmu  = cs + 3 * Hn;
    float* accum  = cs + 4 * Hn;   // [0]=P [1]=Q [2]=pad [3]=ticket

    // 1. zero accumulators + fp32->fp8 convert the 4 weight matrices
    prep_w<<<576, 256, 0, stream>>>(W1m, W2m, W1v, W2v,
                                    W1m_f8, W2m_f8, W1v_f8, W2v_f8,
                                    cs, 4 * Hn + 8);

    // 2. fully fused per-strip MLP + CLUB (256 blocks = 1/CU, 16 waves, 32-row strips)
    club_fused<<<dim3(Bn / 32), 1024, 0, stream>>>(
        modal_a, W1m_f8, W1v_f8, W2m_f8, W2v_f8,
        b1m, b1v, b2m, b2v, modal_b,
        cs, cs2, siv, sivmu, accum, out);
}